// Round 1
// baseline (287.937 us; speedup 1.0000x reference)
//
#include <hip/hip_runtime.h>
#include <math.h>

#define IMG 256
#define N_ANG 360
#define N_DET 256
#define N_SAMP 256
// VOX = 2.0

struct W9 { float w[9]; };

__device__ __forceinline__ int refl(int i, int L) {
    if (i < 0) i = -i;
    if (i >= L) i = 2 * (L - 1) - i;
    return i;
}

// Direct 2D Gaussian blur with reflect indexing (== separable blur w/ reflect pad).
// One thread per output pixel. blockIdx.x = row, blockIdx.y = batch, threadIdx.x = col.
__global__ void blur2d_k(const float* __restrict__ in, float* __restrict__ out,
                         W9 wt, int r, float scale) {
    int x = threadIdx.x;
    int y = blockIdx.x;
    int b = blockIdx.y;
    const float* src = in + b * IMG * IMG;
    float acc = 0.f;
    for (int dy = -r; dy <= r; ++dy) {
        int yy = refl(y + dy, IMG);
        float wy = wt.w[dy + r];
        float rowacc = 0.f;
        const float* rowp = src + yy * IMG;
        for (int dx = -r; dx <= r; ++dx) {
            int xx = refl(x + dx, IMG);
            rowacc += wt.w[dx + r] * rowp[xx];
        }
        acc += wy * rowacc;
    }
    out[b * IMG * IMG + y * IMG + x] = acc * scale;
}

// Parallel-beam projection of BOTH blurred maps (shared geometry).
// blockIdx.x = angle, blockIdx.y = batch, threadIdx.x = detector.
// Geometry replicated in f64 to match numpy's valid-mask boundaries exactly.
__global__ void proj_k(const float* __restrict__ imgb, const float* __restrict__ attb,
                       float* __restrict__ sino_i, float* __restrict__ sino_a) {
    int d = threadIdx.x;
    int a = blockIdx.x;
    int b = blockIdx.y;
    double theta = M_PI * (double)a / (double)N_ANG;
    double c = cos(theta), sn = sin(theta);
    double rr = ((double)d - 127.5) * 2.0;
    const float* ip = imgb + b * IMG * IMG;
    const float* ap = attb + b * IMG * IMG;
    float acc_i = 0.f, acc_a = 0.f;
    for (int k = 0; k < N_SAMP; ++k) {
        double ss = ((double)k - 127.5) * 2.0;
        double x = rr * c - ss * sn;
        double y = rr * sn + ss * c;
        double ixd = x * 0.5 + 127.5;   // x / VOX + (IMG-1)/2
        double iyd = y * 0.5 + 127.5;
        if (ixd >= 0.0 && ixd <= 255.0 && iyd >= 0.0 && iyd <= 255.0) {
            int j0 = (int)floor(ixd); j0 = min(max(j0, 0), IMG - 2);
            int i0 = (int)floor(iyd); i0 = min(max(i0, 0), IMG - 2);
            float fx = (float)(ixd - (double)j0);
            float fy = (float)(iyd - (double)i0);
            float w00 = (1.f - fy) * (1.f - fx);
            float w01 = (1.f - fy) * fx;
            float w10 = fy * (1.f - fx);
            float w11 = fy * fx;
            int o = i0 * IMG + j0;
            acc_i += w00 * ip[o] + w01 * ip[o + 1] + w10 * ip[o + IMG] + w11 * ip[o + IMG + 1];
            acc_a += w00 * ap[o] + w01 * ap[o + 1] + w10 * ap[o + IMG] + w11 * ap[o + IMG + 1];
        }
    }
    int idx = (b * N_ANG + a) * N_DET + d;
    sino_i[idx] = acc_i * 2.0f;  // * VOX
    sino_a[idx] = acc_a * 2.0f;
}

// Attenuate + final blur along DETECTOR axis + transpose to out[b][det][ang].
__global__ void finish_k(const float* __restrict__ sino_i, const float* __restrict__ sino_a,
                         float* __restrict__ out, W9 wt) {
    int tid = blockIdx.x * blockDim.x + threadIdx.x;
    if (tid >= 2 * N_DET * N_ANG) return;
    int a = tid % N_ANG;
    int t = tid / N_ANG;
    int d = t % N_DET;
    int b = t / N_DET;
    float acc = 0.f;
    for (int i = -2; i <= 2; ++i) {
        int dd = refl(d + i, N_DET);
        int idx = (b * N_ANG + a) * N_DET + dd;
        float v = sino_i[idx] * expf(-sino_a[idx] * 2.0f);
        acc += wt.w[i + 2] * v;
    }
    out[tid] = acc;  // tid == (b*N_DET + d)*N_ANG + a
}

static void gauss_w(W9* wt, double sigma, int r) {
    double tmp[9];
    double s = 0.0;
    for (int i = -r; i <= r; ++i) {
        double v = exp(-0.5 * ((double)i / sigma) * ((double)i / sigma));
        tmp[i + r] = v;
        s += v;
    }
    for (int i = 0; i < 2 * r + 1; ++i) wt->w[i] = (float)(tmp[i] / s);
    for (int i = 2 * r + 1; i < 9; ++i) wt->w[i] = 0.f;
}

extern "C" void kernel_launch(void* const* d_in, const int* in_sizes, int n_in,
                              void* d_out, int out_size, void* d_ws, size_t ws_size,
                              hipStream_t stream) {
    const float* img = (const float*)d_in[0];
    const float* att = (const float*)d_in[1];
    float* out = (float*)d_out;

    char* ws = (char*)d_ws;
    float* imgb   = (float*)(ws);                       // 2*256*256 f32 = 512 KiB
    float* attb   = (float*)(ws + 524288);              // 512 KiB
    float* sino_i = (float*)(ws + 1048576);             // 2*360*256 f32 = 720 KiB
    float* sino_a = (float*)(ws + 1785856);             // 720 KiB
    // total ~2.41 MiB of workspace

    double sqrt_log2 = sqrt(log(2.0));
    double sigma_img = 4.0 / (4.0 * sqrt_log2) / 2.0;   // ~0.60056, r=2
    double sigma_att = 4.0 / (2.0 * sqrt_log2) / 2.0;   // ~1.20112, r=4
    W9 wimg, watt;
    gauss_w(&wimg, sigma_img, 2);
    gauss_w(&watt, sigma_att, 4);

    blur2d_k<<<dim3(IMG, 2), IMG, 0, stream>>>(img, imgb, wimg, 2, 1.0f);
    blur2d_k<<<dim3(IMG, 2), IMG, 0, stream>>>(att, attb, watt, 4, 0.01f);
    proj_k<<<dim3(N_ANG, 2), N_DET, 0, stream>>>(imgb, attb, sino_i, sino_a);

    int total = 2 * N_DET * N_ANG;
    finish_k<<<(total + 255) / 256, 256, 0, stream>>>(sino_i, sino_a, out, wimg);
}